// Round 5
// baseline (409.667 us; speedup 1.0000x reference)
//
#include <hip/hip_runtime.h>
#include <stdint.h>

// BaseOpenSetClassifier: per-pixel sq-euclid distance to K templates + min/argmin.
// B=16, N=16384, D=64, K=64, thresholds {0.5, 1.0}.
//
// R12 = R11's compute, double-buffered global_load_lds pipeline (T3 2-phase).
// EVIDENCE (R11): kernel ~135-155us (out of top-5; bench 400 = ~265 fixed +
// kernel), hbm ~13%, no pipe busy. Lockstep stage->barrier->compute phases:
// HBM idle during compute, VALU idle during stage (~26k cyc/CU-round serial
// vs 16k overlapped). Fix = overlap, not occupancy.
// Changes:
//  - Each block owns 4 consecutive pixel-pairs (8 pixels); grid 2048.
//  - LDS double buffer 2x(32KB t + 8KB x) = 80KB -> 2 WGs/CU.
//  - Per tile: issue global_load_lds for tile t+1 FIRST (HBM->LDS direct,
//    5x dwordx4/wave), compute tile t, then ONE __syncthreads() (its
//    vmcnt(0) drain is the buffer handoff; depth-1 pipeline so drain is
//    exactly what's needed -- guide T3 minimal recipe).
//  - XOR swizzle moved to SOURCE side (rule 21: gll dest = linear
//    base+lane*16, can't scatter): per-lane global addr uses i32^(k&7);
//    read side identical to R10/R11's verified st[k*32 + (e^(k&7))].
//  - Fully-unrolled t-loop -> per-tile +512B source offsets constant-fold.
//  - Compute/epilogue/store byte-identical to R11 (R8-exact accumulation,
//    absmax 0.0 provenance; ballot/ffs argmin = first-index ties).
// Budget: steady state HBM-bound 32 tiles/CU x 40KB @ 10.25B/cyc = 53us,
// less with L3 retention (FETCH 164MB < 320MB compulsory) -> predict 40-60us.

#define BB 16
#define NN 16384
#define DD 64
#define KK 64
#define TILES 4

typedef float v2f __attribute__((ext_vector_type(2)));

__device__ __forceinline__ void gll16(const void* g, void* l) {
    // global_load_lds_dwordx4: per-lane global src, wave-uniform LDS base,
    // HW writes base + lane*16 (linear). Width 16 = the m97-verified fast path.
    __builtin_amdgcn_global_load_lds(
        (const __attribute__((address_space(1))) void*)g,
        (__attribute__((address_space(3))) void*)l, 16, 0, 0);
}

__global__ __launch_bounds__(512, 4)
void openset_kernel(const float* __restrict__ x,     // [B,N,D]
                    const float* __restrict__ tmpl,  // [K,N,D]
                    const int*   __restrict__ tcls,  // [K]
                    float*       __restrict__ out) { // [2*B*N | B*N | B*N]
    __shared__ float4 st[2][KK * 32];   // 2 x 32KB: chunk k = t[k, p0:p0+2, :]
    __shared__ float4 sx[2][BB * 32];   // 2 x 8KB : row  b = x[b, p0:p0+2, :]

    const int lane = threadIdx.x & 63;
    const int wv   = threadIdx.x >> 6;          // 0..7
    const int pp   = wv & 1;                    // wave's pixel in the pair
    const int q    = wv >> 1;                   // wave's b-quarter (4 b's)
    const int half = lane >> 5;                 // which chunk/row of a pair
    const int i32  = lane & 31;                 // float4 index within 512B

    // XCD swizzle: XCD i (= blk&7) owns pixels [i*2048, (i+1)*2048), 8/block.
    const int p0b = (int)(((blockIdx.x & 7) << 11) | ((blockIdx.x >> 3) << 3));

    // Per-lane global sources for tile 0; tile t adds t*32 float4 (+512B).
    // t source is PRE-SWIZZLED (i32 ^ (k&7)) so linear LDS + swizzled read
    // compose to the identity (rule 21: same involution both sides).
    const float4* tsrc[4];
#pragma unroll
    for (int c = 0; c < 4; ++c) {
        const int k = (wv * 4 + c) * 2 + half;
        tsrc[c] = (const float4*)(tmpl + ((size_t)k << 20))
                  + (size_t)p0b * 16 + (i32 ^ (k & 7));
    }
    const float4* xsrc = (const float4*)(x + ((size_t)(wv * 2 + half) << 20))
                         + (size_t)p0b * 16 + i32;

    // ---- Prologue: stage tile 0 into buffer 0.
#pragma unroll
    for (int c = 0; c < 4; ++c) gll16(tsrc[c], &st[0][(wv * 4 + c) * 64]);
    gll16(xsrc, &sx[0][wv * 64]);
    __syncthreads();   // drains vmcnt -> tile 0 resident

#pragma unroll
    for (int t = 0; t < TILES; ++t) {
        const int cur = t & 1;

        // ---- Issue next tile's loads BEFORE compute (they fly under it).
        if (t + 1 < TILES) {
            const int nxt = cur ^ 1;
#pragma unroll
            for (int c = 0; c < 4; ++c)
                gll16(tsrc[c] + (t + 1) * 32, &st[nxt][(wv * 4 + c) * 64]);
            gll16(xsrc + (t + 1) * 32, &sx[nxt][wv * 64]);
        }

        // ---- Compute tile t (R8-EXACT accumulation; R11 structure).
        v2f acc[4];
#pragma unroll
        for (int i = 0; i < 4; ++i) acc[i] = (v2f){0.f, 0.f};

#pragma unroll
        for (int h = 0; h < 2; ++h) {
            v2f a0[4], a1[4];
#pragma unroll
            for (int i = 0; i < 4; ++i) {
                a0[i] = (v2f){0.f, 0.f};
                a1[i] = (v2f){0.f, 0.f};
            }
#pragma unroll
            for (int j = 0; j < 8; ++j) {
                const int e = pp * 16 + h * 8 + j;
                const float4 tv = st[cur][lane * 32 + (e ^ (lane & 7))];
#pragma unroll
                for (int i = 0; i < 4; ++i) {
                    const float4 xv = sx[cur][(q * 4 + i) * 32 + e];  // bcast
                    v2f d0 = (v2f){xv.x - tv.x, xv.y - tv.y};
                    v2f d1 = (v2f){xv.z - tv.z, xv.w - tv.w};
                    a0[i] += d0 * d0;      // pk_fma chains, 2-way ILP per b
                    a1[i] += d1 * d1;
                }
            }
#pragma unroll
            for (int i = 0; i < 4; ++i) acc[i] += a0[i] + a1[i];
        }

        // ---- Epilogue (R8-verified): per-b min over 64 lanes (= 64 k's),
        // argmin via ballot+ffs -> first-index ties == jnp.argmin.
        float bestd = 0.f;
        int   bestk = 0;
#pragma unroll
        for (int i = 0; i < 4; ++i) {
            const float dme = acc[i].x + acc[i].y;
            float m = dme;
#pragma unroll
            for (int s = 1; s < 64; s <<= 1)
                m = fminf(m, __shfl_xor(m, s));
            const unsigned long long tie = __ballot(dme == m);
            const int ks = __ffsll(tie) - 1;
            if (lane == i) { bestd = m; bestk = ks; }
        }

        if (lane < 4) {
            const int b = q * 4 + lane;
            const size_t BN = (size_t)BB * NN;
            const size_t o  = (size_t)b * NN + (p0b + 2 * t + pp);
            out[o]          = (bestd <= 0.5f) ? 1.0f : 0.0f;  // masks[0] @0.5
            out[BN + o]     = (bestd <= 1.0f) ? 1.0f : 0.0f;  // masks[1] @1.0
            out[2 * BN + o] = bestd;                          // min_dists
            out[3 * BN + o] = (float)tcls[bestk];             // pred_classes
        }

        // ---- Handoff: drain vmcnt (tile t+1 resident) + phase sync.
        __syncthreads();
    }
}

extern "C" void kernel_launch(void* const* d_in, const int* in_sizes, int n_in,
                              void* d_out, int out_size, void* d_ws, size_t ws_size,
                              hipStream_t stream) {
    const float* x    = (const float*)d_in[0];   // frame_embeddings [16,16384,64]
    const float* tmpl = (const float*)d_in[1];   // templates       [64,16384,64]
    const int*   tcls = (const int*)d_in[2];     // template_classes [64]
    float* out = (float*)d_out;

    dim3 grid(NN / (2 * TILES));  // 2048 blocks: 8 waves, 4 pixel-pairs each
    dim3 block(512);
    openset_kernel<<<grid, block, 0, stream>>>(x, tmpl, tcls, out);
}